// Round 8
// baseline (225.735 us; speedup 1.0000x reference)
//
#include <hip/hip_runtime.h>
#include <math.h>

// Problem constants (AttentionLikeModel_75531294867774)
#define DIMM    1024
#define NHEADS  16
#define HDIM    64
#define BATCH   2
#define SEQ     2048
#define ROWS    (BATCH*SEQ)   // 4096

typedef _Float16 f16x8 __attribute__((ext_vector_type(8)));
typedef _Float16 f16x4 __attribute__((ext_vector_type(4)));
typedef float    f32x4 __attribute__((ext_vector_type(4)));

__device__ inline void gl_lds16(const void* g, void* l) {
    __builtin_amdgcn_global_load_lds(
        (const __attribute__((address_space(1))) void*)g,
        (__attribute__((address_space(3))) void*)l, 16, 0, 0);
}

// ---------------------------------------------------------------------------
// Merged prep: blocks [0,2048) cvt x -> fp16; [2048,2816) W_qkv^T; [2816,3072) W_out^T
// ---------------------------------------------------------------------------
__device__ void tcvt64(const float* __restrict__ in, _Float16* __restrict__ out,
                       int K, int N, int k0, int n0, float (*tile)[65], int t)
{
    {
        const int c4 = (t & 15) * 4;
        const int r  = t >> 4;
        #pragma unroll
        for (int i = 0; i < 4; i++) {
            const int rr = r + 16 * i;
            float4 v = *(const float4*)(in + (size_t)(k0 + rr) * N + n0 + c4);
            tile[rr][c4] = v.x; tile[rr][c4 + 1] = v.y;
            tile[rr][c4 + 2] = v.z; tile[rr][c4 + 3] = v.w;
        }
    }
    __syncthreads();
    #pragma unroll
    for (int i = 0; i < 2; i++) {
        const int seg = t + 256 * i;
        const int n   = seg >> 3;
        const int kc  = (seg & 7) * 8;
        f16x8 o;
        #pragma unroll
        for (int j = 0; j < 8; j++) o[j] = (_Float16)tile[kc + j][n];
        *(f16x8*)(out + (size_t)(n0 + n) * K + k0 + kc) = o;
    }
}

__global__ __launch_bounds__(256)
void prep_kernel(const float* __restrict__ x, const float* __restrict__ Wqkv,
                 const float* __restrict__ Wout, _Float16* __restrict__ xh,
                 _Float16* __restrict__ wqkvt, _Float16* __restrict__ woutt)
{
    __shared__ float tile[64][65];
    const int bx = blockIdx.x;
    const int t  = threadIdx.x;
    if (bx < 2048) {
        const int i = bx * 256 + t;
        const float4 a = *(const float4*)(x + (size_t)i * 8);
        const float4 b = *(const float4*)(x + (size_t)i * 8 + 4);
        f16x8 o;
        o[0] = (_Float16)a.x; o[1] = (_Float16)a.y; o[2] = (_Float16)a.z; o[3] = (_Float16)a.w;
        o[4] = (_Float16)b.x; o[5] = (_Float16)b.y; o[6] = (_Float16)b.z; o[7] = (_Float16)b.w;
        *(f16x8*)(xh + (size_t)i * 8) = o;
    } else if (bx < 2816) {
        const int id = bx - 2048;
        const int gx = id % 48, gy = id / 48;
        tcvt64(Wqkv, wqkvt, DIMM, 3 * DIMM, gy * 64, gx * 64, tile, t);
    } else {
        const int id = bx - 2816;
        const int gx = id & 15, gy = id >> 4;
        tcvt64(Wout, woutt, DIMM, DIMM, gy * 64, gx * 64, tile, t);
    }
}

// ---------------------------------------------------------------------------
// HGEMM + bias, BK=64. MODE 0: fp32 out. MODE 1: qkv — Q/K col-blocks write
// fp16 qkvh; V col-blocks (col0>=2048) write ONLY transposed vtg[bh][d][key].
// ---------------------------------------------------------------------------
template<int MODE>
__global__ __launch_bounds__(256)
void hgemm_bias_kernel(const _Float16* __restrict__ A, const _Float16* __restrict__ Bt,
                       const float* __restrict__ bias, void* __restrict__ Cout,
                       _Float16* __restrict__ vtg, int N, int K)
{
    __shared__ _Float16 As[128 * 64];
    __shared__ _Float16 Bs[128 * 64];

    const int t    = threadIdx.x;
    const int w    = t >> 6, lane = t & 63;
    const int quad = lane >> 4, l16 = lane & 15;
    const int wr   = w >> 1, wc = w & 1;
    const int row0 = blockIdx.y * 128, col0 = blockIdx.x * 128;
    const int sw   = l16 & 7;

    f32x4 acc[4][4];
    #pragma unroll
    for (int i = 0; i < 4; i++)
        #pragma unroll
        for (int j = 0; j < 4; j++)
            #pragma unroll
            for (int r = 0; r < 4; r++) acc[i][j][r] = 0.f;

    const _Float16* gA[4];
    const _Float16* gB[4];
    int lofs[4];
    #pragma unroll
    for (int j = 0; j < 4; j++) {
        const int s   = t + 256 * j;
        const int row = s >> 3;
        const int kb  = (s & 7) ^ (row & 7);
        gA[j] = A  + (size_t)(row0 + row) * K + kb * 8;
        gB[j] = Bt + (size_t)(col0 + row) * K + kb * 8;
        lofs[j] = s * 8;
    }

    const int niter = K >> 6;
    #pragma unroll 1
    for (int it = 0; it < niter; it++) {
        __syncthreads();
        #pragma unroll
        for (int j = 0; j < 4; j++) gl_lds16(gA[j], As + lofs[j]);
        #pragma unroll
        for (int j = 0; j < 4; j++) gl_lds16(gB[j], Bs + lofs[j]);
        #pragma unroll
        for (int j = 0; j < 4; j++) { gA[j] += 64; gB[j] += 64; }
        __syncthreads();

        f16x8 af[4][2], bf[4][2];
        #pragma unroll
        for (int i = 0; i < 4; i++) {
            const int arow = wr * 64 + i * 16 + l16;
            const int brow = wc * 64 + i * 16 + l16;
            #pragma unroll
            for (int hh = 0; hh < 2; hh++) {
                af[i][hh] = *(const f16x8*)(As + (arow * 8 + ((hh * 4 + quad) ^ sw)) * 8);
                bf[i][hh] = *(const f16x8*)(Bs + (brow * 8 + ((hh * 4 + quad) ^ sw)) * 8);
            }
        }
        #pragma unroll
        for (int i = 0; i < 4; i++)
            #pragma unroll
            for (int j = 0; j < 4; j++) {
                acc[i][j] = __builtin_amdgcn_mfma_f32_16x16x32_f16(af[i][0], bf[j][0], acc[i][j], 0, 0, 0);
                acc[i][j] = __builtin_amdgcn_mfma_f32_16x16x32_f16(af[i][1], bf[j][1], acc[i][j], 0, 0, 0);
            }
    }

    const bool vblock = (MODE == 1) && (col0 >= 2 * DIMM);
    #pragma unroll
    for (int j = 0; j < 4; j++) {
        const int col = col0 + wc * 64 + j * 16 + l16;
        const float bv = bias[col];
        #pragma unroll
        for (int i = 0; i < 4; i++) {
            const int row = row0 + wr * 64 + i * 16 + quad * 4;
            if (vblock) {
                const int dg  = col - 2 * DIMM;
                const int h   = dg >> 6, dl = dg & 63;
                const int b   = row >> 11, key = row & (SEQ - 1);
                f16x4 o;
                #pragma unroll
                for (int r = 0; r < 4; r++) o[r] = (_Float16)(acc[i][j][r] + bv);
                *(f16x4*)(vtg + ((size_t)((b * NHEADS + h) * 64 + dl)) * SEQ + key) = o;
            } else {
                #pragma unroll
                for (int r = 0; r < 4; r++) {
                    const float v = acc[i][j][r] + bv;
                    if (MODE == 1)
                        ((_Float16*)Cout)[(size_t)(row + r) * N + col] = (_Float16)v;
                    else
                        ((float*)Cout)[(size_t)(row + r) * N + col] = v;
                }
            }
        }
    }
}

// ---------------------------------------------------------------------------
// MFMA flash attention, register-P k-split-4. Block = 4 waves = one
// (b,h,64-q tile); grid (32,32). Wave w owns keys [16w,16w+16): computes
// S^T strip (2x mfma 16x16x32), exp2 in-register, then PV over its OWN 16
// keys via mfma_f32_16x16x16f16 — the S^T C-layout (key=quad*4+r, q=l16)
// IS the 16x16x16 A-operand layout (m=l16, k=quad*4+j), so P never touches
// LDS. O partials merged across waves once at the end (LDS chain).
// LDS: K 8K + Vt 8K (+1K lbuf) = 17.4 KB; 2 barriers/ktile; no P conflicts.
// ---------------------------------------------------------------------------
__global__ __launch_bounds__(256, 3)
void flash_attn_kernel(const _Float16* __restrict__ qkv,
                       const _Float16* __restrict__ vtg,
                       _Float16* __restrict__ out)
{
    const int qt = blockIdx.x;          // 0..31
    const int bh = blockIdx.y;          // 0..31
    const int b  = bh >> 4, h = bh & 15;
    const int t    = threadIdx.x;
    const int w    = t >> 6;
    const int lane = t & 63;
    const int quad = lane >> 4;
    const int l16  = lane & 15;
    const int sw   = l16 & 7;

    __shared__ __align__(16) _Float16 KVs[8192];   // Ks | Vts; epilogue: Obuf f32[64*64]
    __shared__ float lbuf[256];
    _Float16* Ks  = KVs;
    _Float16* Vts = KVs + 4096;

    const int q0 = qt * 64;
    const size_t rstr = 3 * DIMM;
    const _Float16* qbase = qkv + (size_t)b * SEQ * rstr;

    // ---- Q fragments: register-resident (B-operand of S^T, 16x16x32)
    f16x8 qf[4][2];
    #pragma unroll
    for (int qb = 0; qb < 4; qb++) {
        const _Float16* qrow = qbase + (size_t)(q0 + qb * 16 + l16) * rstr + h * HDIM;
        qf[qb][0] = *(const f16x8*)(qrow + quad * 8);
        qf[qb][1] = *(const f16x8*)(qrow + 32 + quad * 8);
    }

    f32x4 Oacc[4][4];                   // [qb][db], D rows = q = qb*16+quad*4+r
    #pragma unroll
    for (int i = 0; i < 4; i++)
        #pragma unroll
        for (int j = 0; j < 4; j++) Oacc[i][j] = (f32x4){0.f, 0.f, 0.f, 0.f};
    float lrow[4] = {0.f, 0.f, 0.f, 0.f};

    // staging descriptors (two 16B segments each for K and Vt per thread)
    const int seg0 = t, seg1 = t + 256;
    const int r0 = seg0 >> 3, lb0 = (seg0 & 7) ^ (r0 & 7);
    const int r1 = seg1 >> 3, lb1 = (seg1 & 7) ^ (r1 & 7);
    const _Float16* gK0 = qbase + (size_t)r0 * rstr + DIMM + h * HDIM + lb0 * 8;
    const _Float16* gK1 = qbase + (size_t)r1 * rstr + DIMM + h * HDIM + lb1 * 8;
    const _Float16* gV0 = vtg + ((size_t)bh * 64 + r0) * SEQ + lb0 * 8;
    const _Float16* gV1 = vtg + ((size_t)bh * 64 + r1) * SEQ + lb1 * 8;

    const int kAbase = (16 * w + l16) * 64;       // K A-frag row (own strip)
    const int vq     = 2 * w + (quad >> 1);       // Vt key-block (own 16 keys)
    const int vsub   = (quad & 1) * 4;
    const float SCL  = 0.18033688f;               // 0.125 * log2(e)

    #pragma unroll 1
    for (int k0 = 0; k0 < SEQ; k0 += 64) {
        __syncthreads();                          // prior tile's K/V reads done
        gl_lds16(gK0 + (size_t)k0 * rstr, Ks  + seg0 * 8);
        gl_lds16(gK1 + (size_t)k0 * rstr, Ks  + seg1 * 8);
        gl_lds16(gV0 + k0,                Vts + seg0 * 8);
        gl_lds16(gV1 + k0,                Vts + seg1 * 8);
        __syncthreads();                          // staging drained

        // K A-fragments (own 16-key strip)
        f16x8 kf0 = *(const f16x8*)(Ks + kAbase + ((0 + quad) ^ sw) * 8);
        f16x8 kf1 = *(const f16x8*)(Ks + kAbase + ((4 + quad) ^ sw) * 8);
        // Vt B-fragments for PV (own keys, all 64 d; qb-invariant)
        f16x4 vf[4];
        #pragma unroll
        for (int db = 0; db < 4; db++) {
            const int dl = db * 16 + l16;
            vf[db] = *(const f16x4*)(Vts + dl * 64 + ((vq ^ sw) << 3) + vsub);
        }

        #pragma unroll
        for (int qb = 0; qb < 4; qb++) {
            f32x4 s = (f32x4){0.f, 0.f, 0.f, 0.f};
            s = __builtin_amdgcn_mfma_f32_16x16x32_f16(kf0, qf[qb][0], s, 0, 0, 0);
            s = __builtin_amdgcn_mfma_f32_16x16x32_f16(kf1, qf[qb][1], s, 0, 0, 0);
            // plain-exp softmax via native exp2 (v_exp_f32), scale folded
            float p0 = exp2f(s[0] * SCL);
            float p1 = exp2f(s[1] * SCL);
            float p2 = exp2f(s[2] * SCL);
            float p3 = exp2f(s[3] * SCL);
            lrow[qb] += (p0 + p1) + (p2 + p3);
            f16x4 pa;                              // A-frag of 16x16x16: m=l16,k=quad*4+j
            pa[0] = (_Float16)p0; pa[1] = (_Float16)p1;
            pa[2] = (_Float16)p2; pa[3] = (_Float16)p3;
            #pragma unroll
            for (int db = 0; db < 4; db++)
                Oacc[qb][db] = __builtin_amdgcn_mfma_f32_16x16x16f16(pa, vf[db], Oacc[qb][db], 0, 0, 0);
        }
    }

    // ---- l reduce: quads (own-wave 16 keys), then store per-wave partials
    #pragma unroll
    for (int qb = 0; qb < 4; qb++) {
        lrow[qb] += __shfl_xor(lrow[qb], 16);
        lrow[qb] += __shfl_xor(lrow[qb], 32);
    }
    __syncthreads();                               // all K/V reads done; KVs reusable
    if (lane < 16) {
        #pragma unroll
        for (int qb = 0; qb < 4; qb++) lbuf[w * 64 + qb * 16 + lane] = lrow[qb];
    }

    // ---- O merge: 4-wave chain through LDS (Obuf[q][d] f32, 16 KB = KVs)
    float* Obuf = (float*)KVs;
    if (w == 0) {
        #pragma unroll
        for (int qb = 0; qb < 4; qb++)
            #pragma unroll
            for (int db = 0; db < 4; db++)
                #pragma unroll
                for (int r = 0; r < 4; r++)
                    Obuf[(qb * 16 + quad * 4 + r) * 64 + db * 16 + l16] = Oacc[qb][db][r];
    }
    __syncthreads();
    if (w == 1) {
        #pragma unroll
        for (int qb = 0; qb < 4; qb++)
            #pragma unroll
            for (int db = 0; db < 4; db++)
                #pragma unroll
                for (int r = 0; r < 4; r++)
                    Obuf[(qb * 16 + quad * 4 + r) * 64 + db * 16 + l16] += Oacc[qb][db][r];
    }
    __syncthreads();
    if (w == 2) {
        #pragma unroll
        for (int qb = 0; qb < 4; qb++)
            #pragma unroll
            for (int db = 0; db < 4; db++)
                #pragma unroll
                for (int r = 0; r < 4; r++)
                    Obuf[(qb * 16 + quad * 4 + r) * 64 + db * 16 + l16] += Oacc[qb][db][r];
    }
    __syncthreads();
    if (w == 3) {
        #pragma unroll
        for (int qb = 0; qb < 4; qb++)
            #pragma unroll
            for (int db = 0; db < 4; db++)
                #pragma unroll
                for (int r = 0; r < 4; r++)
                    Obuf[(qb * 16 + quad * 4 + r) * 64 + db * 16 + l16] += Oacc[qb][db][r];
    }
    __syncthreads();

    // ---- cooperative normalize + writeout: thread t -> (row=t>>2, 16-d seg)
    {
        const int row = t >> 2, d0 = (t & 3) * 16;
        const float lr = 1.f / (lbuf[row] + lbuf[64 + row] + lbuf[128 + row] + lbuf[192 + row]);
        const float* ob = Obuf + row * 64 + d0;
        f16x8 o0, o1;
        #pragma unroll
        for (int j = 0; j < 8; j++) {
            o0[j] = (_Float16)(ob[j] * lr);
            o1[j] = (_Float16)(ob[8 + j] * lr);
        }
        _Float16* orow = out + (size_t)(b * SEQ + q0 + row) * DIMM + h * HDIM + d0;
        *(f16x8*)orow       = o0;
        *(f16x8*)(orow + 8) = o1;
    }
}

// ---------------------------------------------------------------------------
extern "C" void kernel_launch(void* const* d_in, const int* in_sizes, int n_in,
                              void* d_out, int out_size, void* d_ws, size_t ws_size,
                              hipStream_t stream)
{
    const float* x    = (const float*)d_in[0];   // [2,2048,1024]
    const float* Wqkv = (const float*)d_in[1];   // [1024,3072]
    const float* bqkv = (const float*)d_in[2];   // [3072]
    const float* Wout = (const float*)d_in[3];   // [1024,1024]
    const float* bout = (const float*)d_in[4];   // [1024]
    float* out = (float*)d_out;                  // [2,2048,1024]

    _Float16* qkvh  = (_Float16*)d_ws;                   // 4096x3072 (V third unused)
    _Float16* attnh = qkvh  + (size_t)ROWS * 3 * DIMM;   // 4096x1024
    _Float16* xh    = attnh + (size_t)ROWS * DIMM;       // 4096x1024
    _Float16* wqkvt = xh    + (size_t)ROWS * DIMM;       // 3072x1024
    _Float16* woutt = wqkvt + (size_t)3 * DIMM * DIMM;   // 1024x1024
    _Float16* vtg   = woutt + (size_t)DIMM * DIMM;       // 32 x 64 x 2048

    // 0) merged fp16 conversions (x, W_qkv^T, W_out^T)
    prep_kernel<<<3072, 256, 0, stream>>>(x, Wqkv, Wout, xh, wqkvt, woutt);
    // 1) qkv = x @ W_qkv + b_qkv   (Q/K -> qkvh f16; V -> vtg transposed)
    {
        dim3 grid(3 * DIMM / 128, ROWS / 128);
        hgemm_bias_kernel<1><<<grid, 256, 0, stream>>>(xh, wqkvt, bqkv, qkvh, vtg, 3 * DIMM, DIMM);
    }
    // 2) attention -> attnh (fp16)
    {
        dim3 grid(SEQ / 64, BATCH * NHEADS);     // (32,32)
        flash_attn_kernel<<<grid, 256, 0, stream>>>(qkvh, vtg, attnh);
    }
    // 3) out = attn @ W_out + b_out  (fp32 out)
    {
        dim3 grid(DIMM / 128, ROWS / 128);
        hgemm_bias_kernel<0><<<grid, 256, 0, stream>>>(attnh, woutt, bout, out, nullptr, DIMM, DIMM);
    }
}

// Round 9
// 214.488 us; speedup vs baseline: 1.0524x; 1.0524x over previous
//
#include <hip/hip_runtime.h>
#include <math.h>

// Problem constants (AttentionLikeModel_75531294867774)
#define DIMM    1024
#define NHEADS  16
#define HDIM    64
#define BATCH   2
#define SEQ     2048
#define ROWS    (BATCH*SEQ)   // 4096

typedef _Float16 f16x8 __attribute__((ext_vector_type(8)));
typedef _Float16 f16x4 __attribute__((ext_vector_type(4)));
typedef float    f32x4 __attribute__((ext_vector_type(4)));

__device__ inline void gl_lds16(const void* g, void* l) {
    __builtin_amdgcn_global_load_lds(
        (const __attribute__((address_space(1))) void*)g,
        (__attribute__((address_space(3))) void*)l, 16, 0, 0);
}

// ---------------------------------------------------------------------------
// Merged prep: blocks [0,2048) cvt x -> fp16; [2048,2816) W_qkv^T; [2816,3072) W_out^T
// ---------------------------------------------------------------------------
__device__ void tcvt64(const float* __restrict__ in, _Float16* __restrict__ out,
                       int K, int N, int k0, int n0, float (*tile)[65], int t)
{
    {
        const int c4 = (t & 15) * 4;
        const int r  = t >> 4;
        #pragma unroll
        for (int i = 0; i < 4; i++) {
            const int rr = r + 16 * i;
            float4 v = *(const float4*)(in + (size_t)(k0 + rr) * N + n0 + c4);
            tile[rr][c4] = v.x; tile[rr][c4 + 1] = v.y;
            tile[rr][c4 + 2] = v.z; tile[rr][c4 + 3] = v.w;
        }
    }
    __syncthreads();
    #pragma unroll
    for (int i = 0; i < 2; i++) {
        const int seg = t + 256 * i;
        const int n   = seg >> 3;
        const int kc  = (seg & 7) * 8;
        f16x8 o;
        #pragma unroll
        for (int j = 0; j < 8; j++) o[j] = (_Float16)tile[kc + j][n];
        *(f16x8*)(out + (size_t)(n0 + n) * K + k0 + kc) = o;
    }
}

__global__ __launch_bounds__(256)
void prep_kernel(const float* __restrict__ x, const float* __restrict__ Wqkv,
                 const float* __restrict__ Wout, _Float16* __restrict__ xh,
                 _Float16* __restrict__ wqkvt, _Float16* __restrict__ woutt)
{
    __shared__ float tile[64][65];
    const int bx = blockIdx.x;
    const int t  = threadIdx.x;
    if (bx < 2048) {
        const int i = bx * 256 + t;
        const float4 a = *(const float4*)(x + (size_t)i * 8);
        const float4 b = *(const float4*)(x + (size_t)i * 8 + 4);
        f16x8 o;
        o[0] = (_Float16)a.x; o[1] = (_Float16)a.y; o[2] = (_Float16)a.z; o[3] = (_Float16)a.w;
        o[4] = (_Float16)b.x; o[5] = (_Float16)b.y; o[6] = (_Float16)b.z; o[7] = (_Float16)b.w;
        *(f16x8*)(xh + (size_t)i * 8) = o;
    } else if (bx < 2816) {
        const int id = bx - 2048;
        const int gx = id % 48, gy = id / 48;
        tcvt64(Wqkv, wqkvt, DIMM, 3 * DIMM, gy * 64, gx * 64, tile, t);
    } else {
        const int id = bx - 2816;
        const int gx = id & 15, gy = id >> 4;
        tcvt64(Wout, woutt, DIMM, DIMM, gy * 64, gx * 64, tile, t);
    }
}

// ---------------------------------------------------------------------------
// HGEMM + bias — R3 BK=32 structure (validated fast). MODE 0: fp32 out.
// MODE 1: qkv — Q/K col-blocks write fp16 qkvh; V col-blocks (col0>=2048)
// write ONLY transposed vtg[bh][d][key] (fused V-transpose).
// 128x128x32 tile, 256 thr = 4 waves, each wave 64x64 = 4x4 mfma 16x16x32.
// ---------------------------------------------------------------------------
template<int MODE>
__global__ __launch_bounds__(256)
void hgemm_bias_kernel(const _Float16* __restrict__ A, const _Float16* __restrict__ Bt,
                       const float* __restrict__ bias, void* __restrict__ Cout,
                       _Float16* __restrict__ vtg, int N, int K)
{
    __shared__ _Float16 As[128 * 32];
    __shared__ _Float16 Bs[128 * 32];

    const int t    = threadIdx.x;
    const int w    = t >> 6, lane = t & 63;
    const int quad = lane >> 4, l16 = lane & 15;
    const int wr   = w >> 1, wc = w & 1;
    const int row0 = blockIdx.y * 128, col0 = blockIdx.x * 128;

    f32x4 acc[4][4];
    #pragma unroll
    for (int i = 0; i < 4; i++)
        #pragma unroll
        for (int j = 0; j < 4; j++)
            #pragma unroll
            for (int r = 0; r < 4; r++) acc[i][j][r] = 0.f;

    const int p0 = w * 128 + lane;
    const int p1 = p0 + 64;
    const int rA0 = p0 >> 2, kq0 = (p0 & 3) ^ ((p0 >> 4) & 3);
    const int rA1 = p1 >> 2, kq1 = (p1 & 3) ^ ((p1 >> 4) & 3);

    const _Float16* gA0 = A  + (size_t)(row0 + rA0) * K + kq0 * 8;
    const _Float16* gA1 = A  + (size_t)(row0 + rA1) * K + kq1 * 8;
    const _Float16* gB0 = Bt + (size_t)(col0 + rA0) * K + kq0 * 8;
    const _Float16* gB1 = Bt + (size_t)(col0 + rA1) * K + kq1 * 8;
    _Float16* lA0 = As + p0 * 8;
    _Float16* lA1 = As + p1 * 8;
    _Float16* lB0 = Bs + p0 * 8;
    _Float16* lB1 = Bs + p1 * 8;

    const int sx    = quad ^ ((l16 >> 2) & 3);
    const int abase = ((wr * 64 + l16) * 4 + sx) * 8;
    const int bbase = ((wc * 64 + l16) * 4 + sx) * 8;

    const int niter = K >> 5;
    for (int it = 0; it < niter; it++) {
        __syncthreads();
        gl_lds16(gA0, lA0); gl_lds16(gA1, lA1);
        gl_lds16(gB0, lB0); gl_lds16(gB1, lB1);
        gA0 += 32; gA1 += 32; gB0 += 32; gB1 += 32;
        __syncthreads();

        f16x8 af[4], bf[4];
        #pragma unroll
        for (int i = 0; i < 4; i++) {
            af[i] = *(const f16x8*)(As + abase + i * 512);
            bf[i] = *(const f16x8*)(Bs + bbase + i * 512);
        }
        #pragma unroll
        for (int i = 0; i < 4; i++)
            #pragma unroll
            for (int j = 0; j < 4; j++)
                acc[i][j] = __builtin_amdgcn_mfma_f32_16x16x32_f16(af[i], bf[j], acc[i][j], 0, 0, 0);
    }

    const bool vblock = (MODE == 1) && (col0 >= 2 * DIMM);
    #pragma unroll
    for (int j = 0; j < 4; j++) {
        const int col = col0 + wc * 64 + j * 16 + l16;
        const float bv = bias[col];
        #pragma unroll
        for (int i = 0; i < 4; i++) {
            const int row = row0 + wr * 64 + i * 16 + quad * 4;
            if (vblock) {
                // V block: write transposed into vtg[bh][d][key], 4 keys per b64
                const int dg  = col - 2 * DIMM;
                const int h   = dg >> 6, dl = dg & 63;
                const int b   = row >> 11, key = row & (SEQ - 1);
                f16x4 o;
                #pragma unroll
                for (int r = 0; r < 4; r++) o[r] = (_Float16)(acc[i][j][r] + bv);
                *(f16x4*)(vtg + ((size_t)((b * NHEADS + h) * 64 + dl)) * SEQ + key) = o;
            } else {
                #pragma unroll
                for (int r = 0; r < 4; r++) {
                    const float v = acc[i][j][r] + bv;
                    if (MODE == 1)
                        ((_Float16*)Cout)[(size_t)(row + r) * N + col] = (_Float16)v;
                    else
                        ((float*)Cout)[(size_t)(row + r) * N + col] = v;
                }
            }
        }
    }
}

// ---------------------------------------------------------------------------
// MFMA flash attention — R5 structure (best measured: 65 µs). Block = 4 waves
// = one (b,h,64-q tile); grid (32,32). S^T = K·Q^T with register-resident Q
// fragments; plain-exp softmax via exp2; P through LDS (stride-72);
// O = P·V^T with pre-transposed V (vtg). LDS: K 8K + Vt 8K + P 9.2K = 25.6 KB.
// ---------------------------------------------------------------------------
__global__ __launch_bounds__(256, 4)
void flash_attn_kernel(const _Float16* __restrict__ qkv,
                       const _Float16* __restrict__ vtg,
                       _Float16* __restrict__ out)
{
    const int qt = blockIdx.x;          // 0..31
    const int bh = blockIdx.y;          // 0..31
    const int b  = bh >> 4, h = bh & 15;
    const int t    = threadIdx.x;
    const int w    = t >> 6;
    const int lane = t & 63;
    const int quad = lane >> 4;
    const int l16  = lane & 15;
    const int sw   = l16 & 7;

    __shared__ __align__(16) _Float16 Ks [64 * 64];
    __shared__ __align__(16) _Float16 Vts[64 * 64];
    __shared__ __align__(16) _Float16 Ps [64 * 72];

    const int q0 = qt * 64;
    const size_t rstr = 3 * DIMM;
    const _Float16* qbase = qkv + (size_t)b * SEQ * rstr;

    // ---- Q fragments: register-resident for the whole k-loop
    f16x8 qf[4][2];
    #pragma unroll
    for (int qb = 0; qb < 4; qb++) {
        const _Float16* qrow = qbase + (size_t)(q0 + qb * 16 + l16) * rstr + h * HDIM;
        qf[qb][0] = *(const f16x8*)(qrow + quad * 8);
        qf[qb][1] = *(const f16x8*)(qrow + 32 + quad * 8);
    }

    f32x4 Oacc[4];
    #pragma unroll
    for (int i = 0; i < 4; i++) Oacc[i] = (f32x4){0.f, 0.f, 0.f, 0.f};
    float lrow[4] = {0.f, 0.f, 0.f, 0.f};

    // staging descriptors (two 16B segments each for K and Vt per thread)
    const int seg0 = t, seg1 = t + 256;
    const int r0 = seg0 >> 3, lb0 = (seg0 & 7) ^ (r0 & 7);
    const int r1 = seg1 >> 3, lb1 = (seg1 & 7) ^ (r1 & 7);
    const _Float16* gK0 = qbase + (size_t)r0 * rstr + DIMM + h * HDIM + lb0 * 8;
    const _Float16* gK1 = qbase + (size_t)r1 * rstr + DIMM + h * HDIM + lb1 * 8;
    const _Float16* gV0 = vtg + ((size_t)bh * 64 + r0) * SEQ + lb0 * 8;
    const _Float16* gV1 = vtg + ((size_t)bh * 64 + r1) * SEQ + lb1 * 8;

    const int kAbase = (16 * w + l16) * 64;
    const int pAbase = (16 * w + l16) * 72;
    const float SCL  = 0.18033688f;               // 0.125 * log2(e)

    #pragma unroll 1
    for (int k0 = 0; k0 < SEQ; k0 += 64) {
        __syncthreads();                        // prior PV/P reads done
        gl_lds16(gK0 + (size_t)k0 * rstr, Ks  + seg0 * 8);
        gl_lds16(gK1 + (size_t)k0 * rstr, Ks  + seg1 * 8);
        gl_lds16(gV0 + k0,                Vts + seg0 * 8);
        gl_lds16(gV1 + k0,                Vts + seg1 * 8);
        __syncthreads();                        // staging drained

        // ---- S^T strip: keys [16w,16w+16) x 64 q
        f16x8 kf0 = *(const f16x8*)(Ks + kAbase + ((0 + quad) ^ sw) * 8);
        f16x8 kf1 = *(const f16x8*)(Ks + kAbase + ((4 + quad) ^ sw) * 8);
        #pragma unroll
        for (int qb = 0; qb < 4; qb++) {
            f32x4 s = (f32x4){0.f, 0.f, 0.f, 0.f};
            s = __builtin_amdgcn_mfma_f32_16x16x32_f16(kf0, qf[qb][0], s, 0, 0, 0);
            s = __builtin_amdgcn_mfma_f32_16x16x32_f16(kf1, qf[qb][1], s, 0, 0, 0);
            float p0 = exp2f(s[0] * SCL);
            float p1 = exp2f(s[1] * SCL);
            float p2 = exp2f(s[2] * SCL);
            float p3 = exp2f(s[3] * SCL);
            lrow[qb] += (p0 + p1) + (p2 + p3);
            f16x4 pk;
            pk[0] = (_Float16)p0; pk[1] = (_Float16)p1;
            pk[2] = (_Float16)p2; pk[3] = (_Float16)p3;
            *(f16x4*)(Ps + (qb * 16 + l16) * 72 + 16 * w + 4 * quad) = pk;
        }
        __syncthreads();                        // P complete, K reads done

        // ---- O += P · V^T : q-strip [16w,16w+16) x 64 d
        f16x8 pf0 = *(const f16x8*)(Ps + pAbase + quad * 8);
        f16x8 pf1 = *(const f16x8*)(Ps + pAbase + 32 + quad * 8);
        #pragma unroll
        for (int db = 0; db < 4; db++) {
            const int vrow = db * 16 + l16;
            f16x8 vf0 = *(const f16x8*)(Vts + vrow * 64 + ((0 + quad) ^ sw) * 8);
            f16x8 vf1 = *(const f16x8*)(Vts + vrow * 64 + ((4 + quad) ^ sw) * 8);
            Oacc[db] = __builtin_amdgcn_mfma_f32_16x16x32_f16(pf0, vf0, Oacc[db], 0, 0, 0);
            Oacc[db] = __builtin_amdgcn_mfma_f32_16x16x32_f16(pf1, vf1, Oacc[db], 0, 0, 0);
        }
    }

    // ---- softmax denominator: reduce over quads, then waves (via LDS)
    #pragma unroll
    for (int qb = 0; qb < 4; qb++) {
        lrow[qb] += __shfl_xor(lrow[qb], 16);
        lrow[qb] += __shfl_xor(lrow[qb], 32);
    }
    __syncthreads();                            // all PV done; Ks reusable
    float* lbuf = (float*)Ks;
    if (lane < 16) {
        #pragma unroll
        for (int qb = 0; qb < 4; qb++) lbuf[w * 64 + qb * 16 + lane] = lrow[qb];
    }
    __syncthreads();
    const int qloc = 16 * w + quad * 4;
    float lrec[4];
    #pragma unroll
    for (int r = 0; r < 4; r++) {
        const int q = qloc + r;
        lrec[r] = 1.f / (lbuf[q] + lbuf[64 + q] + lbuf[128 + q] + lbuf[192 + q]);
    }
    #pragma unroll
    for (int db = 0; db < 4; db++) {
        #pragma unroll
        for (int r = 0; r < 4; r++) {
            out[(size_t)(b * SEQ + q0 + qloc + r) * DIMM + h * HDIM + db * 16 + l16] =
                (_Float16)(Oacc[db][r] * lrec[r]);
        }
    }
}

// ---------------------------------------------------------------------------
extern "C" void kernel_launch(void* const* d_in, const int* in_sizes, int n_in,
                              void* d_out, int out_size, void* d_ws, size_t ws_size,
                              hipStream_t stream)
{
    const float* x    = (const float*)d_in[0];   // [2,2048,1024]
    const float* Wqkv = (const float*)d_in[1];   // [1024,3072]
    const float* bqkv = (const float*)d_in[2];   // [3072]
    const float* Wout = (const float*)d_in[3];   // [1024,1024]
    const float* bout = (const float*)d_in[4];   // [1024]
    float* out = (float*)d_out;                  // [2,2048,1024]

    _Float16* qkvh  = (_Float16*)d_ws;                   // 4096x3072 (V third unused)
    _Float16* attnh = qkvh  + (size_t)ROWS * 3 * DIMM;   // 4096x1024
    _Float16* xh    = attnh + (size_t)ROWS * DIMM;       // 4096x1024
    _Float16* wqkvt = xh    + (size_t)ROWS * DIMM;       // 3072x1024
    _Float16* woutt = wqkvt + (size_t)3 * DIMM * DIMM;   // 1024x1024
    _Float16* vtg   = woutt + (size_t)DIMM * DIMM;       // 32 x 64 x 2048

    // 0) merged fp16 conversions (x, W_qkv^T, W_out^T)
    prep_kernel<<<3072, 256, 0, stream>>>(x, Wqkv, Wout, xh, wqkvt, woutt);
    // 1) qkv = x @ W_qkv + b_qkv   (Q/K -> qkvh f16; V -> vtg transposed)
    {
        dim3 grid(3 * DIMM / 128, ROWS / 128);   // (24,32)
        hgemm_bias_kernel<1><<<grid, 256, 0, stream>>>(xh, wqkvt, bqkv, qkvh, vtg, 3 * DIMM, DIMM);
    }
    // 2) attention -> attnh (fp16)
    {
        dim3 grid(SEQ / 64, BATCH * NHEADS);     // (32,32)
        flash_attn_kernel<<<grid, 256, 0, stream>>>(qkvh, vtg, attnh);
    }
    // 3) out = attn @ W_out + b_out  (fp32 out)
    {
        dim3 grid(DIMM / 128, ROWS / 128);       // (8,32)
        hgemm_bias_kernel<0><<<grid, 256, 0, stream>>>(attnh, woutt, bout, out, nullptr, DIMM, DIMM);
    }
}

// Round 10
// 211.192 us; speedup vs baseline: 1.0689x; 1.0156x over previous
//
#include <hip/hip_runtime.h>
#include <math.h>

// Problem constants (AttentionLikeModel_75531294867774)
#define DIMM    1024
#define NHEADS  16
#define HDIM    64
#define BATCH   2
#define SEQ     2048
#define ROWS    (BATCH*SEQ)   // 4096

typedef _Float16 f16x8 __attribute__((ext_vector_type(8)));
typedef _Float16 f16x4 __attribute__((ext_vector_type(4)));
typedef float    f32x4 __attribute__((ext_vector_type(4)));

__device__ inline void gl_lds16(const void* g, void* l) {
    __builtin_amdgcn_global_load_lds(
        (const __attribute__((address_space(1))) void*)g,
        (__attribute__((address_space(3))) void*)l, 16, 0, 0);
}

// Barrier that waits only on LDS ops (lgkmcnt), leaving global_load_lds DMA
// (vmcnt) in flight — the key to overlapping staging with compute.
__device__ inline void barrier_lds_only() {
    __asm__ volatile("s_waitcnt lgkmcnt(0)\n\ts_barrier" ::: "memory");
}

// ---------------------------------------------------------------------------
// Merged prep: blocks [0,2048) cvt x -> fp16; [2048,2816) W_qkv^T; [2816,3072) W_out^T
// ---------------------------------------------------------------------------
__device__ void tcvt64(const float* __restrict__ in, _Float16* __restrict__ out,
                       int K, int N, int k0, int n0, float (*tile)[65], int t)
{
    {
        const int c4 = (t & 15) * 4;
        const int r  = t >> 4;
        #pragma unroll
        for (int i = 0; i < 4; i++) {
            const int rr = r + 16 * i;
            float4 v = *(const float4*)(in + (size_t)(k0 + rr) * N + n0 + c4);
            tile[rr][c4] = v.x; tile[rr][c4 + 1] = v.y;
            tile[rr][c4 + 2] = v.z; tile[rr][c4 + 3] = v.w;
        }
    }
    __syncthreads();
    #pragma unroll
    for (int i = 0; i < 2; i++) {
        const int seg = t + 256 * i;
        const int n   = seg >> 3;
        const int kc  = (seg & 7) * 8;
        f16x8 o;
        #pragma unroll
        for (int j = 0; j < 8; j++) o[j] = (_Float16)tile[kc + j][n];
        *(f16x8*)(out + (size_t)(n0 + n) * K + k0 + kc) = o;
    }
}

__global__ __launch_bounds__(256)
void prep_kernel(const float* __restrict__ x, const float* __restrict__ Wqkv,
                 const float* __restrict__ Wout, _Float16* __restrict__ xh,
                 _Float16* __restrict__ wqkvt, _Float16* __restrict__ woutt)
{
    __shared__ float tile[64][65];
    const int bx = blockIdx.x;
    const int t  = threadIdx.x;
    if (bx < 2048) {
        const int i = bx * 256 + t;
        const float4 a = *(const float4*)(x + (size_t)i * 8);
        const float4 b = *(const float4*)(x + (size_t)i * 8 + 4);
        f16x8 o;
        o[0] = (_Float16)a.x; o[1] = (_Float16)a.y; o[2] = (_Float16)a.z; o[3] = (_Float16)a.w;
        o[4] = (_Float16)b.x; o[5] = (_Float16)b.y; o[6] = (_Float16)b.z; o[7] = (_Float16)b.w;
        *(f16x8*)(xh + (size_t)i * 8) = o;
    } else if (bx < 2816) {
        const int id = bx - 2048;
        const int gx = id % 48, gy = id / 48;
        tcvt64(Wqkv, wqkvt, DIMM, 3 * DIMM, gy * 64, gx * 64, tile, t);
    } else {
        const int id = bx - 2816;
        const int gx = id & 15, gy = id >> 4;
        tcvt64(Wout, woutt, DIMM, DIMM, gy * 64, gx * 64, tile, t);
    }
}

// ---------------------------------------------------------------------------
// HGEMM + bias, BK=32, LDS double-buffered with ONE barrier per k-tile:
// stage tile k+1 into buf^1 right after the barrier, compute tile k from buf.
// The barrier's implicit vmcnt(0) is the DMA drain for tile k (issued one
// full iteration earlier -> latency hidden).
// MODE 0: fp32 out. MODE 1: qkv — Q/K col-blocks write fp16 qkvh; V
// col-blocks (col0>=2048) write ONLY transposed vtg[bh][d][key].
// ---------------------------------------------------------------------------
template<int MODE>
__global__ __launch_bounds__(256)
void hgemm_bias_kernel(const _Float16* __restrict__ A, const _Float16* __restrict__ Bt,
                       const float* __restrict__ bias, void* __restrict__ Cout,
                       _Float16* __restrict__ vtg, int N, int K)
{
    __shared__ _Float16 As[2][128 * 32];
    __shared__ _Float16 Bs[2][128 * 32];

    const int t    = threadIdx.x;
    const int w    = t >> 6, lane = t & 63;
    const int quad = lane >> 4, l16 = lane & 15;
    const int wr   = w >> 1, wc = w & 1;
    const int row0 = blockIdx.y * 128, col0 = blockIdx.x * 128;

    f32x4 acc[4][4];
    #pragma unroll
    for (int i = 0; i < 4; i++)
        #pragma unroll
        for (int j = 0; j < 4; j++)
            #pragma unroll
            for (int r = 0; r < 4; r++) acc[i][j][r] = 0.f;

    const int p0 = w * 128 + lane;
    const int p1 = p0 + 64;
    const int rA0 = p0 >> 2, kq0 = (p0 & 3) ^ ((p0 >> 4) & 3);
    const int rA1 = p1 >> 2, kq1 = (p1 & 3) ^ ((p1 >> 4) & 3);

    const _Float16* gA0 = A  + (size_t)(row0 + rA0) * K + kq0 * 8;
    const _Float16* gA1 = A  + (size_t)(row0 + rA1) * K + kq1 * 8;
    const _Float16* gB0 = Bt + (size_t)(col0 + rA0) * K + kq0 * 8;
    const _Float16* gB1 = Bt + (size_t)(col0 + rA1) * K + kq1 * 8;
    const int o0 = p0 * 8, o1 = p1 * 8;

    const int sx    = quad ^ ((l16 >> 2) & 3);
    const int abase = ((wr * 64 + l16) * 4 + sx) * 8;
    const int bbase = ((wc * 64 + l16) * 4 + sx) * 8;

    // prologue: stage tile 0 into buf 0
    gl_lds16(gA0, As[0] + o0); gl_lds16(gA1, As[0] + o1);
    gl_lds16(gB0, Bs[0] + o0); gl_lds16(gB1, Bs[0] + o1);
    gA0 += 32; gA1 += 32; gB0 += 32; gB1 += 32;

    const int niter = K >> 5;
    #pragma unroll 1
    for (int it = 0; it < niter; it++) {
        const int cur = it & 1;
        __syncthreads();                 // drains tile-it DMA; buf cur ready
        if (it + 1 < niter) {            // stage tile it+1 into the other buf
            gl_lds16(gA0, As[cur ^ 1] + o0); gl_lds16(gA1, As[cur ^ 1] + o1);
            gl_lds16(gB0, Bs[cur ^ 1] + o0); gl_lds16(gB1, Bs[cur ^ 1] + o1);
            gA0 += 32; gA1 += 32; gB0 += 32; gB1 += 32;
        }

        f16x8 af[4], bf[4];
        #pragma unroll
        for (int i = 0; i < 4; i++) {
            af[i] = *(const f16x8*)(As[cur] + abase + i * 512);
            bf[i] = *(const f16x8*)(Bs[cur] + bbase + i * 512);
        }
        #pragma unroll
        for (int i = 0; i < 4; i++)
            #pragma unroll
            for (int j = 0; j < 4; j++)
                acc[i][j] = __builtin_amdgcn_mfma_f32_16x16x32_f16(af[i], bf[j], acc[i][j], 0, 0, 0);
    }

    const bool vblock = (MODE == 1) && (col0 >= 2 * DIMM);
    #pragma unroll
    for (int j = 0; j < 4; j++) {
        const int col = col0 + wc * 64 + j * 16 + l16;
        const float bv = bias[col];
        #pragma unroll
        for (int i = 0; i < 4; i++) {
            const int row = row0 + wr * 64 + i * 16 + quad * 4;
            if (vblock) {
                // V block: write transposed into vtg[bh][d][key], 4 keys per b64
                const int dg  = col - 2 * DIMM;
                const int h   = dg >> 6, dl = dg & 63;
                const int b   = row >> 11, key = row & (SEQ - 1);
                f16x4 o;
                #pragma unroll
                for (int r = 0; r < 4; r++) o[r] = (_Float16)(acc[i][j][r] + bv);
                *(f16x4*)(vtg + ((size_t)((b * NHEADS + h) * 64 + dl)) * SEQ + key) = o;
            } else {
                #pragma unroll
                for (int r = 0; r < 4; r++) {
                    const float v = acc[i][j][r] + bv;
                    if (MODE == 1)
                        ((_Float16*)Cout)[(size_t)(row + r) * N + col] = (_Float16)v;
                    else
                        ((float*)Cout)[(size_t)(row + r) * N + col] = v;
                }
            }
        }
    }
}

// ---------------------------------------------------------------------------
// MFMA flash attention — R5 structure (best measured 65 µs, __expf) + LDS
// double-buffered K/V staging. Per k-tile: top __syncthreads drains tile-k
// DMA (issued one iteration earlier), then tile k+1 is staged into buf^1 and
// stays in flight across the mid P-barrier, which is a raw
// "s_waitcnt lgkmcnt(0); s_barrier" (LDS-only drain — vmcnt untouched).
// LDS: K 2x8K + Vt 2x8K + P 9.2K + lbuf 1K = 42.2 KB -> 3 blocks/CU.
// ---------------------------------------------------------------------------
__global__ __launch_bounds__(256, 3)
void flash_attn_kernel(const _Float16* __restrict__ qkv,
                       const _Float16* __restrict__ vtg,
                       _Float16* __restrict__ out)
{
    const int qt = blockIdx.x;          // 0..31
    const int bh = blockIdx.y;          // 0..31
    const int b  = bh >> 4, h = bh & 15;
    const int t    = threadIdx.x;
    const int w    = t >> 6;
    const int lane = t & 63;
    const int quad = lane >> 4;
    const int l16  = lane & 15;
    const int sw   = l16 & 7;

    __shared__ __align__(16) _Float16 Kbuf[2][4096];
    __shared__ __align__(16) _Float16 Vbuf[2][4096];
    __shared__ __align__(16) _Float16 Ps[64 * 72];
    __shared__ float lbuf[256];

    const int q0 = qt * 64;
    const size_t rstr = 3 * DIMM;
    const _Float16* qbase = qkv + (size_t)b * SEQ * rstr;

    // ---- Q fragments: register-resident for the whole k-loop
    f16x8 qf[4][2];
    #pragma unroll
    for (int qb = 0; qb < 4; qb++) {
        const _Float16* qrow = qbase + (size_t)(q0 + qb * 16 + l16) * rstr + h * HDIM;
        qf[qb][0] = *(const f16x8*)(qrow + quad * 8);
        qf[qb][1] = *(const f16x8*)(qrow + 32 + quad * 8);
    }

    f32x4 Oacc[4];
    #pragma unroll
    for (int i = 0; i < 4; i++) Oacc[i] = (f32x4){0.f, 0.f, 0.f, 0.f};
    float lrow[4] = {0.f, 0.f, 0.f, 0.f};

    // staging descriptors (two 16B segments each for K and Vt per thread)
    const int seg0 = t, seg1 = t + 256;
    const int r0 = seg0 >> 3, lb0 = (seg0 & 7) ^ (r0 & 7);
    const int r1 = seg1 >> 3, lb1 = (seg1 & 7) ^ (r1 & 7);
    const _Float16* gK0 = qbase + (size_t)r0 * rstr + DIMM + h * HDIM + lb0 * 8;
    const _Float16* gK1 = qbase + (size_t)r1 * rstr + DIMM + h * HDIM + lb1 * 8;
    const _Float16* gV0 = vtg + ((size_t)bh * 64 + r0) * SEQ + lb0 * 8;
    const _Float16* gV1 = vtg + ((size_t)bh * 64 + r1) * SEQ + lb1 * 8;

    const int kAbase = (16 * w + l16) * 64;
    const int pAbase = (16 * w + l16) * 72;

    // prologue: stage tile 0 into buf 0
    gl_lds16(gK0, Kbuf[0] + seg0 * 8);
    gl_lds16(gK1, Kbuf[0] + seg1 * 8);
    gl_lds16(gV0, Vbuf[0] + seg0 * 8);
    gl_lds16(gV1, Vbuf[0] + seg1 * 8);

    #pragma unroll 1
    for (int it = 0; it < SEQ / 64; it++) {
        const int cur = it & 1;
        __syncthreads();                        // drains tile-it DMA; prior P/V reads done
        if (it + 1 < SEQ / 64) {                // stage tile it+1 (overlaps this tile's compute)
            const size_t ko = (size_t)(it + 1) * 64;
            gl_lds16(gK0 + ko * rstr, Kbuf[cur ^ 1] + seg0 * 8);
            gl_lds16(gK1 + ko * rstr, Kbuf[cur ^ 1] + seg1 * 8);
            gl_lds16(gV0 + ko,        Vbuf[cur ^ 1] + seg0 * 8);
            gl_lds16(gV1 + ko,        Vbuf[cur ^ 1] + seg1 * 8);
        }
        const _Float16* Ks  = Kbuf[cur];
        const _Float16* Vts = Vbuf[cur];

        // ---- S^T strip: keys [16w,16w+16) x 64 q
        f16x8 kf0 = *(const f16x8*)(Ks + kAbase + ((0 + quad) ^ sw) * 8);
        f16x8 kf1 = *(const f16x8*)(Ks + kAbase + ((4 + quad) ^ sw) * 8);
        #pragma unroll
        for (int qb = 0; qb < 4; qb++) {
            f32x4 s = (f32x4){0.f, 0.f, 0.f, 0.f};
            s = __builtin_amdgcn_mfma_f32_16x16x32_f16(kf0, qf[qb][0], s, 0, 0, 0);
            s = __builtin_amdgcn_mfma_f32_16x16x32_f16(kf1, qf[qb][1], s, 0, 0, 0);
            float p0 = __expf(s[0] * 0.125f);
            float p1 = __expf(s[1] * 0.125f);
            float p2 = __expf(s[2] * 0.125f);
            float p3 = __expf(s[3] * 0.125f);
            lrow[qb] += (p0 + p1) + (p2 + p3);
            f16x4 pk;
            pk[0] = (_Float16)p0; pk[1] = (_Float16)p1;
            pk[2] = (_Float16)p2; pk[3] = (_Float16)p3;
            *(f16x4*)(Ps + (qb * 16 + l16) * 72 + 16 * w + 4 * quad) = pk;
        }
        barrier_lds_only();                     // P visible; DMA stays in flight

        // ---- O += P · V^T : q-strip [16w,16w+16) x 64 d
        f16x8 pf0 = *(const f16x8*)(Ps + pAbase + quad * 8);
        f16x8 pf1 = *(const f16x8*)(Ps + pAbase + 32 + quad * 8);
        #pragma unroll
        for (int db = 0; db < 4; db++) {
            const int vrow = db * 16 + l16;
            f16x8 vf0 = *(const f16x8*)(Vts + vrow * 64 + ((0 + quad) ^ sw) * 8);
            f16x8 vf1 = *(const f16x8*)(Vts + vrow * 64 + ((4 + quad) ^ sw) * 8);
            Oacc[db] = __builtin_amdgcn_mfma_f32_16x16x32_f16(pf0, vf0, Oacc[db], 0, 0, 0);
            Oacc[db] = __builtin_amdgcn_mfma_f32_16x16x32_f16(pf1, vf1, Oacc[db], 0, 0, 0);
        }
    }

    // ---- softmax denominator: reduce over quads, then waves (via LDS)
    #pragma unroll
    for (int qb = 0; qb < 4; qb++) {
        lrow[qb] += __shfl_xor(lrow[qb], 16);
        lrow[qb] += __shfl_xor(lrow[qb], 32);
    }
    if (lane < 16) {
        #pragma unroll
        for (int qb = 0; qb < 4; qb++) lbuf[w * 64 + qb * 16 + lane] = lrow[qb];
    }
    __syncthreads();
    const int qloc = 16 * w + quad * 4;
    float lrec[4];
    #pragma unroll
    for (int r = 0; r < 4; r++) {
        const int q = qloc + r;
        lrec[r] = 1.f / (lbuf[q] + lbuf[64 + q] + lbuf[128 + q] + lbuf[192 + q]);
    }
    #pragma unroll
    for (int db = 0; db < 4; db++) {
        #pragma unroll
        for (int r = 0; r < 4; r++) {
            out[(size_t)(b * SEQ + q0 + qloc + r) * DIMM + h * HDIM + db * 16 + l16] =
                (_Float16)(Oacc[db][r] * lrec[r]);
        }
    }
}

// ---------------------------------------------------------------------------
extern "C" void kernel_launch(void* const* d_in, const int* in_sizes, int n_in,
                              void* d_out, int out_size, void* d_ws, size_t ws_size,
                              hipStream_t stream)
{
    const float* x    = (const float*)d_in[0];   // [2,2048,1024]
    const float* Wqkv = (const float*)d_in[1];   // [1024,3072]
    const float* bqkv = (const float*)d_in[2];   // [3072]
    const float* Wout = (const float*)d_in[3];   // [1024,1024]
    const float* bout = (const float*)d_in[4];   // [1024]
    float* out = (float*)d_out;                  // [2,2048,1024]

    _Float16* qkvh  = (_Float16*)d_ws;                   // 4096x3072 (V third unused)
    _Float16* attnh = qkvh  + (size_t)ROWS * 3 * DIMM;   // 4096x1024
    _Float16* xh    = attnh + (size_t)ROWS * DIMM;       // 4096x1024
    _Float16* wqkvt = xh    + (size_t)ROWS * DIMM;       // 3072x1024
    _Float16* woutt = wqkvt + (size_t)3 * DIMM * DIMM;   // 1024x1024
    _Float16* vtg   = woutt + (size_t)DIMM * DIMM;       // 32 x 64 x 2048

    // 0) merged fp16 conversions (x, W_qkv^T, W_out^T)
    prep_kernel<<<3072, 256, 0, stream>>>(x, Wqkv, Wout, xh, wqkvt, woutt);
    // 1) qkv = x @ W_qkv + b_qkv   (Q/K -> qkvh f16; V -> vtg transposed)
    {
        dim3 grid(3 * DIMM / 128, ROWS / 128);   // (24,32)
        hgemm_bias_kernel<1><<<grid, 256, 0, stream>>>(xh, wqkvt, bqkv, qkvh, vtg, 3 * DIMM, DIMM);
    }
    // 2) attention -> attnh (fp16)
    {
        dim3 grid(SEQ / 64, BATCH * NHEADS);     // (32,32)
        flash_attn_kernel<<<grid, 256, 0, stream>>>(qkvh, vtg, attnh);
    }
    // 3) out = attn @ W_out + b_out  (fp32 out)
    {
        dim3 grid(DIMM / 128, ROWS / 128);       // (8,32)
        hgemm_bias_kernel<0><<<grid, 256, 0, stream>>>(attnh, woutt, bout, out, nullptr, DIMM, DIMM);
    }
}